// Round 1
// baseline (1306.895 us; speedup 1.0000x reference)
//
#include <hip/hip_runtime.h>
#include <hip/hip_bf16.h>
#include <math.h>

#define NRES 2048
#define BATCH 4
#define TOPK 48
#define EDGEF 128
// atoms ids: n=0, ca=1, c=2, o=3, cb=4
__constant__ int c_an[24] = {0,2,3,4,1,1,1,1,0,0,0,4,4,3,0,2,3,4,2,3,4,2,3,2};
__constant__ int c_bn[24] = {0,2,3,4,0,2,3,4,2,3,4,2,3,2,1,1,1,1,0,0,0,4,4,3};

// ---------------- kernel A: virtual C-beta + atom SoA ----------------
__global__ __launch_bounds__(256) void atoms_kernel(const float* __restrict__ x,
                                                    float* __restrict__ atoms) {
  int r = blockIdx.x * 256 + threadIdx.x;
  if (r >= BATCH * NRES) return;
  const float* xr = x + (size_t)r * 12;
  float nx = xr[0], ny = xr[1], nz = xr[2];
  float cax = xr[3], cay = xr[4], caz = xr[5];
  float cx = xr[6], cy = xr[7], cz = xr[8];
  float ox = xr[9], oy = xr[10], oz = xr[11];
  float bx = cax - nx, by = cay - ny, bz = caz - nz;
  float vx = cx - cax, vy = cy - cay, vz = cz - caz;
  float axp = by * vz - bz * vy;
  float ayp = bz * vx - bx * vz;
  float azp = bx * vy - by * vx;
  float cbx = -0.58273431f * axp + 0.56802827f * bx - 0.54067466f * vx + cax;
  float cby = -0.58273431f * ayp + 0.56802827f * by - 0.54067466f * vy + cay;
  float cbz = -0.58273431f * azp + 0.56802827f * bz - 0.54067466f * vz + caz;
  float* ar = atoms + (size_t)r * 15;
  ar[0] = nx;  ar[1] = ny;  ar[2] = nz;
  ar[3] = cax; ar[4] = cay; ar[5] = caz;
  ar[6] = cx;  ar[7] = cy;  ar[8] = cz;
  ar[9] = ox;  ar[10] = oy; ar[11] = oz;
  ar[12] = cbx; ar[13] = cby; ar[14] = cbz;
}

// ---------------- kernel B: masked distances + exact top-48 ----------------
// One wave per row i; 4 rows (same batch) per 256-thread block sharing CA LDS.
// Distances computed with _rn intrinsics (no FMA contraction) to match numpy
// fp32 rounding bitwise, so rank order + tie-break(lower index) match JAX top_k.
__global__ __launch_bounds__(256) void topk_kernel(const float* __restrict__ atoms,
                                                   const float* __restrict__ mask,
                                                   int* __restrict__ nidx,
                                                   float* __restrict__ dnb,
                                                   float* __restrict__ idx_out) {
  __shared__ float cax[NRES], cay[NRES], caz[NRES], msk[NRES];
  int tid = threadIdx.x;
  int r0 = blockIdx.x * 4;
  int b = r0 / NRES;
  int base = b * NRES;
  for (int j = tid; j < NRES; j += 256) {
    const float* ar = atoms + (size_t)(base + j) * 15;
    cax[j] = ar[3]; cay[j] = ar[4]; caz[j] = ar[5];
    msk[j] = mask[base + j];
  }
  __syncthreads();
  int w = tid >> 6, lane = tid & 63;
  int i = r0 + w;
  int il = i - base;
  float pix = cax[il], piy = cay[il], piz = caz[il];
  float mi = msk[il];
  float dv[32];
  float lmax = 0.f;
#pragma unroll
  for (int s = 0; s < 32; ++s) {
    int j = s * 64 + lane;
    float dx = __fsub_rn(pix, cax[j]);
    float dy = __fsub_rn(piy, cay[j]);
    float dz = __fsub_rn(piz, caz[j]);
    float s2 = __fadd_rn(__fadd_rn(__fmul_rn(dx, dx), __fmul_rn(dy, dy)), __fmul_rn(dz, dz));
    float d = __fmul_rn(__fmul_rn(mi, msk[j]), __fsqrt_rn(__fadd_rn(s2, 1e-6f)));
    dv[s] = d;
    lmax = fmaxf(lmax, d);
  }
#pragma unroll
  for (int m = 32; m >= 1; m >>= 1) lmax = fmaxf(lmax, __shfl_xor(lmax, m, 64));
#pragma unroll
  for (int s = 0; s < 32; ++s) {
    int j = s * 64 + lane;
    float m2 = __fmul_rn(mi, msk[j]);
    dv[s] = __fadd_rn(dv[s], __fmul_rn(__fsub_rn(1.f, m2), lmax));
  }
  float lastv = -INFINITY;
  int lastj = -1;
  for (int it = 0; it < TOPK; ++it) {
    float bv = INFINITY;
    int bj = 0x7fffffff;
#pragma unroll
    for (int s = 0; s < 32; ++s) {
      float v = dv[s];
      int j = s * 64 + lane;
      bool valid = (v > lastv) || (v == lastv && j > lastj);
      bool better = (v < bv) || (v == bv && j < bj);
      if (valid && better) { bv = v; bj = j; }
    }
#pragma unroll
    for (int m = 32; m >= 1; m >>= 1) {
      float ov = __shfl_xor(bv, m, 64);
      int oj = __shfl_xor(bj, m, 64);
      if ((ov < bv) || (ov == bv && oj < bj)) { bv = ov; bj = oj; }
    }
    lastv = bv; lastj = bj;
    if (lane == 0) {
      size_t o = (size_t)i * TOPK + it;
      nidx[o] = bj;
      dnb[o] = bv;
      idx_out[o] = (float)bj;
    }
  }
}

// ---------------- kernel C: features + [32x416]@[416x128] + LayerNorm ------
__global__ __launch_bounds__(256) void edge_kernel(const float* __restrict__ atoms,
                                                   const int* __restrict__ nidx,
                                                   const float* __restrict__ dnb,
                                                   const int* __restrict__ ridx,
                                                   const int* __restrict__ chains,
                                                   const float* __restrict__ w_pos,
                                                   const float* __restrict__ b_pos,
                                                   const float* __restrict__ w_edge,
                                                   const float* __restrict__ gamma,
                                                   const float* __restrict__ beta,
                                                   float* __restrict__ out) {
  __shared__ int sr[32], sjg[32], senc[32];
  __shared__ float sdist[32][25];
  __shared__ float feat[32][420];  // 416 padded to 420 (16B-aligned rows)
  int tid = threadIdx.x;
  long e0 = (long)blockIdx.x * 32;
  if (tid < 32) {
    long e = e0 + tid;
    int r = (int)(e / TOPK);
    int b = r >> 11;
    int j = nidx[e];
    int jg = (b << 11) + j;
    sr[tid] = r;
    sjg[tid] = jg;
    int off = ridx[r] - ridx[jg];
    int same = (chains[r] == chains[jg]) ? 1 : 0;
    senc[tid] = same ? min(max(off + 32, 0), 64) : 65;
    sdist[tid][0] = dnb[e];
  }
  __syncthreads();
  for (int t = tid; t < 32 * 24; t += 256) {
    int le = t / 24, p = t % 24;
    const float* ai = atoms + (size_t)sr[le] * 15 + c_an[p] * 3;
    const float* bj = atoms + (size_t)sjg[le] * 15 + c_bn[p] * 3;
    float dx = ai[0] - bj[0], dy = ai[1] - bj[1], dz = ai[2] - bj[2];
    sdist[le][p + 1] = sqrtf(dx * dx + dy * dy + dz * dz + 1e-6f);
  }
  __syncthreads();
  for (int t = tid; t < 32 * 416; t += 256) {
    int le = t / 416, c = t % 416;
    float val;
    if (c < 16) {
      val = w_pos[senc[le] * 16 + c] + b_pos[c];
    } else {
      int p = (c - 16) >> 4, bin = (c - 16) & 15;
      float d = sdist[le][p];
      float mu = 2.0f + (20.0f / 15.0f) * bin;
      float u = (d - mu) * 0.8f;
      val = __expf(-u * u);
    }
    feat[le][c] = val;
  }
  __syncthreads();
  // GEMM: thread -> 4 edges (eg*4..+3) x 4 cols (cg*4..+3)
  int cg = tid & 31;
  int eg = tid >> 5;
  float acc[4][4];
#pragma unroll
  for (int e = 0; e < 4; ++e)
#pragma unroll
    for (int c = 0; c < 4; ++c) acc[e][c] = 0.f;
  for (int kk = 0; kk < 416; kk += 4) {
    float4 w0 = *(const float4*)(w_edge + (kk + 0) * 128 + cg * 4);
    float4 w1 = *(const float4*)(w_edge + (kk + 1) * 128 + cg * 4);
    float4 w2 = *(const float4*)(w_edge + (kk + 2) * 128 + cg * 4);
    float4 w3 = *(const float4*)(w_edge + (kk + 3) * 128 + cg * 4);
#pragma unroll
    for (int e = 0; e < 4; ++e) {
      float4 av = *(const float4*)(&feat[eg * 4 + e][kk]);
      acc[e][0] += av.x * w0.x + av.y * w1.x + av.z * w2.x + av.w * w3.x;
      acc[e][1] += av.x * w0.y + av.y * w1.y + av.z * w2.y + av.w * w3.y;
      acc[e][2] += av.x * w0.z + av.y * w1.z + av.z * w2.z + av.w * w3.z;
      acc[e][3] += av.x * w0.w + av.y * w1.w + av.z * w2.w + av.w * w3.w;
    }
  }
  // LayerNorm over 128 cols (spread across the 32-lane half-wave) + store
  float g[4], bt[4];
#pragma unroll
  for (int c = 0; c < 4; ++c) {
    g[c] = gamma[cg * 4 + c];
    bt[c] = beta[cg * 4 + c];
  }
#pragma unroll
  for (int e = 0; e < 4; ++e) {
    float s = acc[e][0] + acc[e][1] + acc[e][2] + acc[e][3];
    float ss = acc[e][0] * acc[e][0] + acc[e][1] * acc[e][1] +
               acc[e][2] * acc[e][2] + acc[e][3] * acc[e][3];
#pragma unroll
    for (int m = 16; m >= 1; m >>= 1) {
      s += __shfl_xor(s, m, 64);
      ss += __shfl_xor(ss, m, 64);
    }
    float mu = s * (1.f / 128.f);
    float var = ss * (1.f / 128.f) - mu * mu;
    float rstd = rsqrtf(var + 1e-5f);
    int le = eg * 4 + e;
    float4 ov;
    ov.x = (acc[e][0] - mu) * rstd * g[0] + bt[0];
    ov.y = (acc[e][1] - mu) * rstd * g[1] + bt[1];
    ov.z = (acc[e][2] - mu) * rstd * g[2] + bt[2];
    ov.w = (acc[e][3] - mu) * rstd * g[3] + bt[3];
    *(float4*)(out + (size_t)(e0 + le) * 128 + cg * 4) = ov;
  }
}

extern "C" void kernel_launch(void* const* d_in, const int* in_sizes, int n_in,
                              void* d_out, int out_size, void* d_ws, size_t ws_size,
                              hipStream_t stream) {
  const float* x = (const float*)d_in[0];
  const float* mask = (const float*)d_in[1];
  const int* ridx = (const int*)d_in[2];
  const int* chains = (const int*)d_in[3];
  const float* w_pos = (const float*)d_in[4];
  const float* b_pos = (const float*)d_in[5];
  const float* w_edge = (const float*)d_in[6];
  const float* gamma = (const float*)d_in[7];
  const float* beta = (const float*)d_in[8];
  float* out = (float*)d_out;

  const size_t n_rows = (size_t)BATCH * NRES;            // 8192
  const size_t n_edges = n_rows * TOPK;                  // 393216
  float* atoms = (float*)d_ws;                           // n_rows*15 floats
  int* nidx = (int*)((char*)d_ws + 4 * n_rows * 15);     // n_edges ints
  float* dnb = (float*)((char*)d_ws + 4 * (n_rows * 15 + n_edges));  // n_edges floats
  float* idx_out = out + n_edges * EDGEF;                // e_idx (as float) after e

  atoms_kernel<<<(int)((n_rows + 255) / 256), 256, 0, stream>>>(x, atoms);
  topk_kernel<<<(int)(n_rows / 4), 256, 0, stream>>>(atoms, mask, nidx, dnb, idx_out);
  edge_kernel<<<(int)(n_edges / 32), 256, 0, stream>>>(atoms, nidx, dnb, ridx, chains,
                                                       w_pos, b_pos, w_edge, gamma,
                                                       beta, out);
}

// Round 3
// 637.207 us; speedup vs baseline: 2.0510x; 2.0510x over previous
//
#include <hip/hip_runtime.h>
#include <hip/hip_bf16.h>
#include <math.h>

#define NRES 2048
#define BATCH 4
#define TOPK 48
#define EDGEF 128
// atoms ids: n=0, ca=1, c=2, o=3, cb=4
__constant__ int c_an[24] = {0,2,3,4,1,1,1,1,0,0,0,4,4,3,0,2,3,4,2,3,4,2,3,2};
__constant__ int c_bn[24] = {0,2,3,4,0,2,3,4,2,3,4,2,3,2,1,1,1,1,0,0,0,4,4,3};

typedef short short8 __attribute__((ext_vector_type(8)));
typedef float f32x4 __attribute__((ext_vector_type(4)));

__device__ __forceinline__ short f2bf(float f) {
  __bf16 h = (__bf16)f;
  return __builtin_bit_cast(short, h);
}

// ---------------- kernel A: virtual C-beta + atom SoA (16-float rows) -------
__global__ __launch_bounds__(256) void atoms_kernel(const float* __restrict__ x,
                                                    float* __restrict__ atoms) {
  int r = blockIdx.x * 256 + threadIdx.x;
  if (r >= BATCH * NRES) return;
  const float* xr = x + (size_t)r * 12;
  float nx = xr[0], ny = xr[1], nz = xr[2];
  float cax = xr[3], cay = xr[4], caz = xr[5];
  float cx = xr[6], cy = xr[7], cz = xr[8];
  float ox = xr[9], oy = xr[10], oz = xr[11];
  float bx = cax - nx, by = cay - ny, bz = caz - nz;
  float vx = cx - cax, vy = cy - cay, vz = cz - caz;
  float axp = by * vz - bz * vy;
  float ayp = bz * vx - bx * vz;
  float azp = bx * vy - by * vx;
  float cbx = -0.58273431f * axp + 0.56802827f * bx - 0.54067466f * vx + cax;
  float cby = -0.58273431f * ayp + 0.56802827f * by - 0.54067466f * vy + cay;
  float cbz = -0.58273431f * azp + 0.56802827f * bz - 0.54067466f * vz + caz;
  float* ar = atoms + (size_t)r * 16;
  ar[0] = nx;  ar[1] = ny;  ar[2] = nz;
  ar[3] = cax; ar[4] = cay; ar[5] = caz;
  ar[6] = cx;  ar[7] = cy;  ar[8] = cz;
  ar[9] = ox;  ar[10] = oy; ar[11] = oz;
  ar[12] = cbx; ar[13] = cby; ar[14] = cbz;
  ar[15] = 0.0f;
}

// ---------------- kernel B: masked distances + exact top-48 ----------------
__global__ __launch_bounds__(256) void topk_kernel(const float* __restrict__ atoms,
                                                   const float* __restrict__ mask,
                                                   int* __restrict__ nidx,
                                                   float* __restrict__ dnb,
                                                   float* __restrict__ idx_out) {
  __shared__ float cax[NRES], cay[NRES], caz[NRES], msk[NRES];
  int tid = threadIdx.x;
  int r0 = blockIdx.x * 4;
  int b = r0 / NRES;
  int base = b * NRES;
  for (int j = tid; j < NRES; j += 256) {
    const float* ar = atoms + (size_t)(base + j) * 16;
    cax[j] = ar[3]; cay[j] = ar[4]; caz[j] = ar[5];
    msk[j] = mask[base + j];
  }
  __syncthreads();
  int w = tid >> 6, lane = tid & 63;
  int i = r0 + w;
  int il = i - base;
  float pix = cax[il], piy = cay[il], piz = caz[il];
  float mi = msk[il];
  float dv[32];
  float lmax = 0.f;
#pragma unroll
  for (int s = 0; s < 32; ++s) {
    int j = s * 64 + lane;
    float dx = __fsub_rn(pix, cax[j]);
    float dy = __fsub_rn(piy, cay[j]);
    float dz = __fsub_rn(piz, caz[j]);
    float s2 = __fadd_rn(__fadd_rn(__fmul_rn(dx, dx), __fmul_rn(dy, dy)), __fmul_rn(dz, dz));
    float d = __fmul_rn(__fmul_rn(mi, msk[j]), __fsqrt_rn(__fadd_rn(s2, 1e-6f)));
    dv[s] = d;
    lmax = fmaxf(lmax, d);
  }
#pragma unroll
  for (int m = 32; m >= 1; m >>= 1) lmax = fmaxf(lmax, __shfl_xor(lmax, m, 64));
#pragma unroll
  for (int s = 0; s < 32; ++s) {
    int j = s * 64 + lane;
    float m2 = __fmul_rn(mi, msk[j]);
    dv[s] = __fadd_rn(dv[s], __fmul_rn(__fsub_rn(1.f, m2), lmax));
  }
  float lastv = -INFINITY;
  int lastj = -1;
  for (int it = 0; it < TOPK; ++it) {
    float bv = INFINITY;
    int bj = 0x7fffffff;
#pragma unroll
    for (int s = 0; s < 32; ++s) {
      float v = dv[s];
      int j = s * 64 + lane;
      bool valid = (v > lastv) || (v == lastv && j > lastj);
      bool better = (v < bv) || (v == bv && j < bj);
      if (valid && better) { bv = v; bj = j; }
    }
#pragma unroll
    for (int m = 32; m >= 1; m >>= 1) {
      float ov = __shfl_xor(bv, m, 64);
      int oj = __shfl_xor(bj, m, 64);
      if ((ov < bv) || (ov == bv && oj < bj)) { bv = ov; bj = oj; }
    }
    lastv = bv; lastj = bj;
    if (lane == 0) {
      size_t o = (size_t)i * TOPK + it;
      nidx[o] = bj;
      dnb[o] = bv;
      idx_out[o] = (float)bj;
    }
  }
}

// ---------------- kernel P: prepack w_edge -> bf16 B-fragment layout -------
// Bpk[((nt*13+kt)*64+lane)*8 + i] = bf16(w_edge[(32kt + (lane>>4)*8 + i)*128 + nt*16 + (lane&15)])
__global__ __launch_bounds__(256) void prepack_kernel(const float* __restrict__ w_edge,
                                                      unsigned short* __restrict__ Bpk) {
  int t = blockIdx.x * 256 + threadIdx.x;
  if (t >= 8 * 13 * 64) return;
  int lane = t & 63, rest = t >> 6;
  int kt = rest % 13, nt = rest / 13;
  int k0 = kt * 32 + (lane >> 4) * 8;
  int col = nt * 16 + (lane & 15);
  unsigned short* dst = Bpk + (size_t)t * 8;
#pragma unroll
  for (int i = 0; i < 8; ++i)
    dst[i] = (unsigned short)f2bf(w_edge[(size_t)(k0 + i) * 128 + col]);
}

// ---------------- kernel C: MFMA edge features + GEMM + LayerNorm ----------
// 256 threads = 4 waves; each wave: 32 edges x 128 cols. 128 edges/block.
__global__ __launch_bounds__(256) void edge_mfma_kernel(
    const float* __restrict__ atoms, const int* __restrict__ nidx,
    const float* __restrict__ dnb, const int* __restrict__ ridx,
    const int* __restrict__ chains, const float* __restrict__ w_pos,
    const float* __restrict__ b_pos, const unsigned short* __restrict__ Bpk,
    const float* __restrict__ gamma, const float* __restrict__ beta,
    float* __restrict__ out) {
  __shared__ __align__(16) char Blds[3][8192];   // triple-buffered B slices
  __shared__ float Dlds[128][26];                // per-edge distances D[0..24]
  __shared__ int sI[128], sJ[128], sEnc[128];

  const int tid = threadIdx.x;
  const int lane = tid & 63, wv = tid >> 6;
  const int q = lane >> 4, r = lane & 15;
  const int h = q >> 1, qb = q & 1;
  const long E0 = (long)blockIdx.x * 128;

  // stage B slice kt=0 into buf0 early (latency hidden under prologue)
#pragma unroll
  for (int u2 = 0; u2 < 2; ++u2) {
    int nt = wv * 2 + u2;
    const unsigned short* g = Bpk + ((size_t)(nt * 13 + 0) * 64 + lane) * 8;
    __builtin_amdgcn_global_load_lds(
        (const __attribute__((address_space(1))) void*)g,
        (__attribute__((address_space(3))) void*)&Blds[0][nt * 1024], 16, 0, 0);
  }

  // phase 0a: per-edge indices, CA-CA dist, positional encoding index
  if (tid < 128) {
    long e = E0 + tid;
    int ir = (int)(e / TOPK);
    int jg = ((ir >> 11) << 11) + nidx[e];
    sI[tid] = ir; sJ[tid] = jg;
    Dlds[tid][0] = dnb[e];
    int off = ridx[ir] - ridx[jg];
    sEnc[tid] = (chains[ir] == chains[jg]) ? min(max(off + 32, 0), 64) : 65;
  }
  __syncthreads();
  // phase 0b: 24 pair distances per edge (cooperative, 12 per thread)
  for (int idx = tid; idx < 128 * 24; idx += 256) {
    int el = idx / 24, p = idx - el * 24;
    const float* ai = atoms + (size_t)sI[el] * 16 + c_an[p] * 3;
    const float* aj = atoms + (size_t)sJ[el] * 16 + c_bn[p] * 3;
    float dx = ai[0] - aj[0], dy = ai[1] - aj[1], dz = ai[2] - aj[2];
    Dlds[el][p + 1] = sqrtf(dx * dx + dy * dy + dz * dz + 1e-6f);
  }
  __syncthreads();

  // per-lane prologue: positional values for this lane's k-columns (kt=0, h==0)
  const int el0 = wv * 32 + r;
  const int el1 = el0 + 16;
  const int senc0 = sEnc[el0], senc1 = sEnc[el1];
  const int cb0 = qb * 8;
  float pv0[8], pv1[8];
#pragma unroll
  for (int i = 0; i < 8; ++i) {
    float bp = b_pos[cb0 + i];
    pv0[i] = w_pos[senc0 * 16 + cb0 + i] + bp;
    pv1[i] = w_pos[senc1 * 16 + cb0 + i] + bp;
  }
  const float mubase = 2.0f + 1.33333333f * (float)cb0;

  f32x4 acc[2][8];
#pragma unroll
  for (int t = 0; t < 2; ++t)
#pragma unroll
    for (int nt = 0; nt < 8; ++nt) acc[t][nt] = (f32x4){0.f, 0.f, 0.f, 0.f};

#pragma unroll
  for (int kt = 0; kt < 13; ++kt) {
    // ---- A fragments computed inline (no LDS for A) ----
    short8 a0, a1;
    if (kt == 0) {
      float d0 = Dlds[el0][0], d1 = Dlds[el1][0];
      float dm0 = (d0 - mubase) * 0.8f, dm1 = (d1 - mubase) * 0.8f;
#pragma unroll
      for (int i = 0; i < 8; ++i) {
        float u0 = dm0 - 1.06666667f * (float)i;
        float u1 = dm1 - 1.06666667f * (float)i;
        float f0 = __expf(-u0 * u0);
        float f1 = __expf(-u1 * u1);
        if (h == 0) { f0 = pv0[i]; f1 = pv1[i]; }   // cndmask, no divergence
        a0[i] = f2bf(f0); a1[i] = f2bf(f1);
      }
    } else {
      float x0 = Dlds[el0][2 * kt - 1], y0 = Dlds[el0][2 * kt];
      float x1 = Dlds[el1][2 * kt - 1], y1 = Dlds[el1][2 * kt];
      float d0 = h ? y0 : x0, d1 = h ? y1 : x1;
      float dm0 = (d0 - mubase) * 0.8f, dm1 = (d1 - mubase) * 0.8f;
#pragma unroll
      for (int i = 0; i < 8; ++i) {
        float u0 = dm0 - 1.06666667f * (float)i;
        float u1 = dm1 - 1.06666667f * (float)i;
        a0[i] = f2bf(__expf(-u0 * u0));
        a1[i] = f2bf(__expf(-u1 * u1));
      }
    }
    // ---- prefetch next B slice; counted vmcnt (never 0 mid-loop) ----
    if (kt < 12) {
#pragma unroll
      for (int u2 = 0; u2 < 2; ++u2) {
        int nt = wv * 2 + u2;
        const unsigned short* g = Bpk + ((size_t)(nt * 13 + kt + 1) * 64 + lane) * 8;
        __builtin_amdgcn_global_load_lds(
            (const __attribute__((address_space(1))) void*)g,
            (__attribute__((address_space(3))) void*)&Blds[(kt + 1) % 3][nt * 1024], 16, 0, 0);
      }
      asm volatile("s_waitcnt vmcnt(2)" ::: "memory");
    } else {
      asm volatile("s_waitcnt vmcnt(0)" ::: "memory");
    }
    __builtin_amdgcn_s_barrier();
    // ---- MFMA: 8 N-tiles x 2 M-tiles ----
    const char* bb = Blds[kt % 3];
#pragma unroll
    for (int nt = 0; nt < 8; ++nt) {
      short8 bf = *(const short8*)(bb + nt * 1024 + lane * 16);
      acc[0][nt] = __builtin_amdgcn_mfma_f32_16x16x32_bf16(a0, bf, acc[0][nt], 0, 0, 0);
      acc[1][nt] = __builtin_amdgcn_mfma_f32_16x16x32_bf16(a1, bf, acc[1][nt], 0, 0, 0);
    }
  }

  // ---- epilogue: LayerNorm over 128 cols (16 lanes x 8 nt) + store ----
  float gg[8], bb8[8];
#pragma unroll
  for (int nt = 0; nt < 8; ++nt) {
    gg[nt] = gamma[nt * 16 + r];
    bb8[nt] = beta[nt * 16 + r];
  }
#pragma unroll
  for (int t = 0; t < 2; ++t) {
#pragma unroll
    for (int reg = 0; reg < 4; ++reg) {
      float s = 0.f, ss = 0.f;
#pragma unroll
      for (int nt = 0; nt < 8; ++nt) {
        float v = acc[t][nt][reg];
        s += v; ss += v * v;
      }
#pragma unroll
      for (int m = 1; m <= 8; m <<= 1) {
        s += __shfl_xor(s, m, 64);
        ss += __shfl_xor(ss, m, 64);
      }
      float mu = s * (1.0f / 128.0f);
      float var = ss * (1.0f / 128.0f) - mu * mu;
      float rstd = rsqrtf(var + 1e-5f);
      long grow = E0 + wv * 32 + t * 16 + q * 4 + reg;
      float* op = out + grow * 128 + r;
#pragma unroll
      for (int nt = 0; nt < 8; ++nt)
        op[nt * 16] = (acc[t][nt][reg] - mu) * rstd * gg[nt] + bb8[nt];
    }
  }
}

extern "C" void kernel_launch(void* const* d_in, const int* in_sizes, int n_in,
                              void* d_out, int out_size, void* d_ws, size_t ws_size,
                              hipStream_t stream) {
  const float* x = (const float*)d_in[0];
  const float* mask = (const float*)d_in[1];
  const int* ridx = (const int*)d_in[2];
  const int* chains = (const int*)d_in[3];
  const float* w_pos = (const float*)d_in[4];
  const float* b_pos = (const float*)d_in[5];
  const float* w_edge = (const float*)d_in[6];
  const float* gamma = (const float*)d_in[7];
  const float* beta = (const float*)d_in[8];
  float* out = (float*)d_out;

  const size_t n_rows = (size_t)BATCH * NRES;   // 8192
  const size_t n_edges = n_rows * TOPK;         // 393216
  float* atoms = (float*)d_ws;                                        // 8192*16 f
  int* nidx = (int*)((char*)d_ws + 4 * n_rows * 16);                  // n_edges i
  float* dnb = (float*)((char*)d_ws + 4 * (n_rows * 16 + n_edges));   // n_edges f
  unsigned short* Bpk =
      (unsigned short*)((char*)d_ws + 4 * (n_rows * 16 + 2 * n_edges));  // 53248 bf16
  float* idx_out = out + n_edges * EDGEF;

  atoms_kernel<<<(int)((n_rows + 255) / 256), 256, 0, stream>>>(x, atoms);
  prepack_kernel<<<26, 256, 0, stream>>>(w_edge, Bpk);
  topk_kernel<<<(int)(n_rows / 4), 256, 0, stream>>>(atoms, mask, nidx, dnb, idx_out);
  edge_mfma_kernel<<<(int)(n_edges / 128), 256, 0, stream>>>(
      atoms, nidx, dnb, ridx, chains, w_pos, b_pos, Bpk, gamma, beta, out);
}

// Round 5
// 402.338 us; speedup vs baseline: 3.2482x; 1.5838x over previous
//
#include <hip/hip_runtime.h>
#include <hip/hip_bf16.h>
#include <math.h>

#define NRES 2048
#define BATCH 4
#define TOPK 48
#define EDGEF 128
// atoms ids: n=0, ca=1, c=2, o=3, cb=4
__constant__ int c_an[24] = {0,2,3,4,1,1,1,1,0,0,0,4,4,3,0,2,3,4,2,3,4,2,3,2};
__constant__ int c_bn[24] = {0,2,3,4,0,2,3,4,2,3,4,2,3,2,1,1,1,1,0,0,0,4,4,3};

typedef short short8 __attribute__((ext_vector_type(8)));
typedef float f32x4 __attribute__((ext_vector_type(4)));

__device__ __forceinline__ short f2bf(float f) {
  __bf16 h = (__bf16)f;
  return __builtin_bit_cast(short, h);
}

__device__ __forceinline__ unsigned long long shfl_xor_u64(unsigned long long v, int m) {
  unsigned lo = (unsigned)v, hi = (unsigned)(v >> 32);
  lo = (unsigned)__shfl_xor((int)lo, m, 64);
  hi = (unsigned)__shfl_xor((int)hi, m, 64);
  return ((unsigned long long)hi << 32) | lo;
}

// ---------------- kernel A: virtual C-beta + atom SoA (16-float rows) -------
__global__ __launch_bounds__(256) void atoms_kernel(const float* __restrict__ x,
                                                    float* __restrict__ atoms) {
  int r = blockIdx.x * 256 + threadIdx.x;
  if (r >= BATCH * NRES) return;
  const float* xr = x + (size_t)r * 12;
  float nx = xr[0], ny = xr[1], nz = xr[2];
  float cax = xr[3], cay = xr[4], caz = xr[5];
  float cx = xr[6], cy = xr[7], cz = xr[8];
  float ox = xr[9], oy = xr[10], oz = xr[11];
  float bx = cax - nx, by = cay - ny, bz = caz - nz;
  float vx = cx - cax, vy = cy - cay, vz = cz - caz;
  float axp = by * vz - bz * vy;
  float ayp = bz * vx - bx * vz;
  float azp = bx * vy - by * vx;
  float cbx = -0.58273431f * axp + 0.56802827f * bx - 0.54067466f * vx + cax;
  float cby = -0.58273431f * ayp + 0.56802827f * by - 0.54067466f * vy + cay;
  float cbz = -0.58273431f * azp + 0.56802827f * bz - 0.54067466f * vz + caz;
  float* ar = atoms + (size_t)r * 16;
  ar[0] = nx;  ar[1] = ny;  ar[2] = nz;
  ar[3] = cax; ar[4] = cay; ar[5] = caz;
  ar[6] = cx;  ar[7] = cy;  ar[8] = cz;
  ar[9] = ox;  ar[10] = oy; ar[11] = oz;
  ar[12] = cbx; ar[13] = cby; ar[14] = cbz;
  ar[15] = 0.0f;
}

// ---------------- kernel B: masked distances + exact top-48 ----------------
// u64 key = (f32bits(d_adj) << 32) | j  — ascending u64 == ascending distance,
// ties by lower index — identical total order to JAX top_k(-d).
// Per-lane sorted cache of 4 smallest; tournament extraction; rare refills.
__global__ __launch_bounds__(256, 4) void topk_kernel(const float* __restrict__ atoms,
                                                      const float* __restrict__ mask,
                                                      int* __restrict__ nidx,
                                                      float* __restrict__ dnb,
                                                      float* __restrict__ idx_out) {
  __shared__ float cax[NRES], cay[NRES], caz[NRES], msk[NRES];
  int tid = threadIdx.x;
  int r0 = blockIdx.x * 4;
  int base = (r0 >> 11) << 11;
  for (int j = tid; j < NRES; j += 256) {
    const float* ar = atoms + (size_t)(base + j) * 16;
    cax[j] = ar[3]; cay[j] = ar[4]; caz[j] = ar[5];
    msk[j] = mask[base + j];
  }
  __syncthreads();
  int w = tid >> 6, lane = tid & 63;
  int i = r0 + w;
  int il = i - base;
  float pix = cax[il], piy = cay[il], piz = caz[il];
  float mi = msk[il];
  float dv[32];
  float lmax = 0.f;
#pragma unroll
  for (int s = 0; s < 32; ++s) {
    int j = s * 64 + lane;
    float dx = __fsub_rn(pix, cax[j]);
    float dy = __fsub_rn(piy, cay[j]);
    float dz = __fsub_rn(piz, caz[j]);
    float s2 = __fadd_rn(__fadd_rn(__fmul_rn(dx, dx), __fmul_rn(dy, dy)), __fmul_rn(dz, dz));
    float d = __fmul_rn(__fmul_rn(mi, msk[j]), __fsqrt_rn(__fadd_rn(s2, 1e-6f)));
    dv[s] = d;
    lmax = fmaxf(lmax, d);
  }
#pragma unroll
  for (int m = 32; m >= 1; m >>= 1) lmax = fmaxf(lmax, __shfl_xor(lmax, m, 64));
  // build u64 keys (adjusted distance bits, index)
  unsigned long long k[32];
#pragma unroll
  for (int s = 0; s < 32; ++s) {
    int j = s * 64 + lane;
    float m2 = __fmul_rn(mi, msk[j]);
    float dadj = __fadd_rn(dv[s], __fmul_rn(__fsub_rn(1.f, m2), lmax));
    k[s] = ((unsigned long long)__float_as_uint(dadj) << 32) | (unsigned)j;
  }
  const unsigned long long SENT = ~0ull;
  // sorted cache of 4 smallest (insertion pass)
  unsigned long long c0 = SENT, c1 = SENT, c2 = SENT, c3 = SENT;
#pragma unroll
  for (int s = 0; s < 32; ++s) {
    unsigned long long K = k[s];
    bool b0 = K < c0, b1 = K < c1, b2 = K < c2, b3 = K < c3;
    c3 = b2 ? c2 : (b3 ? K : c3);
    c2 = b1 ? c1 : (b2 ? K : c2);
    c1 = b0 ? c0 : (b1 ? K : c1);
    c0 = b0 ? K : c0;
  }
  int rem = 4;
  bool exhausted = false;
  unsigned long long last = 0;
  unsigned long long keep = 0;
  for (int it = 0; it < TOPK; ++it) {
    unsigned long long m = c0;
#pragma unroll
    for (int x = 32; x >= 1; x >>= 1) {
      unsigned long long o = shfl_xor_u64(m, x);
      m = (o < m) ? o : m;
    }
    if (it == lane) keep = m;      // lane 'it' keeps result #it
    bool win = (c0 == m);
    c0 = win ? c1 : c0;
    c1 = win ? c2 : c1;
    c2 = win ? c3 : c2;
    c3 = win ? SENT : c3;
    rem = win ? rem - 1 : rem;
    last = m;
    if (__any(rem == 0 && !exhausted)) {   // rare uniform-skipped refill
      if (rem == 0 && !exhausted) {
        unsigned long long p = last;
        unsigned long long n0 = SENT, n1 = SENT, n2 = SENT, n3 = SENT;
#pragma unroll
        for (int s = 0; s < 32; ++s) { unsigned long long K = k[s]; n0 = (K > p && K < n0) ? K : n0; }
#pragma unroll
        for (int s = 0; s < 32; ++s) { unsigned long long K = k[s]; n1 = (K > n0 && K < n1) ? K : n1; }
#pragma unroll
        for (int s = 0; s < 32; ++s) { unsigned long long K = k[s]; n2 = (K > n1 && K < n2) ? K : n2; }
#pragma unroll
        for (int s = 0; s < 32; ++s) { unsigned long long K = k[s]; n3 = (K > n2 && K < n3) ? K : n3; }
        c0 = n0; c1 = n1; c2 = n2; c3 = n3;
        rem = (n0 != SENT) + (n1 != SENT) + (n2 != SENT) + (n3 != SENT);
        exhausted = (rem == 0);
      }
    }
  }
  if (lane < TOPK) {
    size_t o = (size_t)i * TOPK + lane;
    int bj = (int)(unsigned)(keep & 0xffffffffu);
    float bv = __uint_as_float((unsigned)(keep >> 32));
    nidx[o] = bj;
    dnb[o] = bv;
    idx_out[o] = (float)bj;
  }
}

// ---------------- kernel P: prepack w_edge -> bf16 B-fragment layout -------
// Bpk[((nt*13+kt)*64+lane)*8 + i] = bf16(w_edge[(32kt + (lane>>4)*8 + i)*128 + nt*16 + (lane&15)])
__global__ __launch_bounds__(256) void prepack_kernel(const float* __restrict__ w_edge,
                                                      unsigned short* __restrict__ Bpk) {
  int t = blockIdx.x * 256 + threadIdx.x;
  if (t >= 8 * 13 * 64) return;
  int lane = t & 63, rest = t >> 6;
  int kt = rest % 13, nt = rest / 13;
  int k0 = kt * 32 + (lane >> 4) * 8;
  int col = nt * 16 + (lane & 15);
  unsigned short* dst = Bpk + (size_t)t * 8;
#pragma unroll
  for (int i = 0; i < 8; ++i)
    dst[i] = (unsigned short)f2bf(w_edge[(size_t)(k0 + i) * 128 + col]);
}

// ---------------- kernel C: MFMA edge features + GEMM + LayerNorm ----------
// 256 threads = 4 waves; each wave: 32 edges x 128 cols. 128 edges/block.
__global__ __launch_bounds__(256) void edge_mfma_kernel(
    const float* __restrict__ atoms, const int* __restrict__ nidx,
    const float* __restrict__ dnb, const int* __restrict__ ridx,
    const int* __restrict__ chains, const float* __restrict__ w_pos,
    const float* __restrict__ b_pos, const unsigned short* __restrict__ Bpk,
    const float* __restrict__ gamma, const float* __restrict__ beta,
    float* __restrict__ out) {
  __shared__ __align__(16) char Blds[3][8192];   // triple-buffered B slices
  __shared__ float Dlds[128][26];                // per-edge distances D[0..24]
  __shared__ int sI[128], sJ[128], sEnc[128];

  const int tid = threadIdx.x;
  const int lane = tid & 63, wv = tid >> 6;
  const int q = lane >> 4, r = lane & 15;
  const int h = q >> 1, qb = q & 1;
  const long E0 = (long)blockIdx.x * 128;

  // stage B slice kt=0 into buf0 early (latency hidden under prologue)
#pragma unroll
  for (int u2 = 0; u2 < 2; ++u2) {
    int nt = wv * 2 + u2;
    const unsigned short* g = Bpk + ((size_t)(nt * 13 + 0) * 64 + lane) * 8;
    __builtin_amdgcn_global_load_lds(
        (const __attribute__((address_space(1))) void*)g,
        (__attribute__((address_space(3))) void*)&Blds[0][nt * 1024], 16, 0, 0);
  }

  // phase 0a: per-edge indices, CA-CA dist, positional encoding index
  if (tid < 128) {
    long e = E0 + tid;
    int ir = (int)(e / TOPK);
    int jg = ((ir >> 11) << 11) + nidx[e];
    sI[tid] = ir; sJ[tid] = jg;
    Dlds[tid][0] = dnb[e];
    int off = ridx[ir] - ridx[jg];
    sEnc[tid] = (chains[ir] == chains[jg]) ? min(max(off + 32, 0), 64) : 65;
  }
  __syncthreads();
  // phase 0b: 24 pair distances per edge (cooperative, 12 per thread)
  for (int idx = tid; idx < 128 * 24; idx += 256) {
    int el = idx / 24, p = idx - el * 24;
    const float* ai = atoms + (size_t)sI[el] * 16 + c_an[p] * 3;
    const float* aj = atoms + (size_t)sJ[el] * 16 + c_bn[p] * 3;
    float dx = ai[0] - aj[0], dy = ai[1] - aj[1], dz = ai[2] - aj[2];
    Dlds[el][p + 1] = sqrtf(dx * dx + dy * dy + dz * dz + 1e-6f);
  }
  __syncthreads();

  // per-lane prologue: positional values for this lane's k-columns (kt=0, h==0)
  const int el0 = wv * 32 + r;
  const int el1 = el0 + 16;
  const int senc0 = sEnc[el0], senc1 = sEnc[el1];
  const int cb0 = qb * 8;
  float pv0[8], pv1[8];
#pragma unroll
  for (int i = 0; i < 8; ++i) {
    float bp = b_pos[cb0 + i];
    pv0[i] = w_pos[senc0 * 16 + cb0 + i] + bp;
    pv1[i] = w_pos[senc1 * 16 + cb0 + i] + bp;
  }
  const float mubase = 2.0f + 1.33333333f * (float)cb0;

  f32x4 acc[2][8];
#pragma unroll
  for (int t = 0; t < 2; ++t)
#pragma unroll
    for (int nt = 0; nt < 8; ++nt) acc[t][nt] = (f32x4){0.f, 0.f, 0.f, 0.f};

#pragma unroll
  for (int kt = 0; kt < 13; ++kt) {
    // ---- A fragments computed inline (no LDS for A) ----
    short8 a0, a1;
    if (kt == 0) {
      float d0 = Dlds[el0][0], d1 = Dlds[el1][0];
      float dm0 = (d0 - mubase) * 0.8f, dm1 = (d1 - mubase) * 0.8f;
#pragma unroll
      for (int i = 0; i < 8; ++i) {
        float u0 = dm0 - 1.06666667f * (float)i;
        float u1 = dm1 - 1.06666667f * (float)i;
        float f0 = __expf(-u0 * u0);
        float f1 = __expf(-u1 * u1);
        if (h == 0) { f0 = pv0[i]; f1 = pv1[i]; }   // cndmask, no divergence
        a0[i] = f2bf(f0); a1[i] = f2bf(f1);
      }
    } else {
      float x0 = Dlds[el0][2 * kt - 1], y0 = Dlds[el0][2 * kt];
      float x1 = Dlds[el1][2 * kt - 1], y1 = Dlds[el1][2 * kt];
      float d0 = h ? y0 : x0, d1 = h ? y1 : x1;
      float dm0 = (d0 - mubase) * 0.8f, dm1 = (d1 - mubase) * 0.8f;
#pragma unroll
      for (int i = 0; i < 8; ++i) {
        float u0 = dm0 - 1.06666667f * (float)i;
        float u1 = dm1 - 1.06666667f * (float)i;
        a0[i] = f2bf(__expf(-u0 * u0));
        a1[i] = f2bf(__expf(-u1 * u1));
      }
    }
    // ---- prefetch next B slice; counted vmcnt (never 0 mid-loop) ----
    if (kt < 12) {
#pragma unroll
      for (int u2 = 0; u2 < 2; ++u2) {
        int nt = wv * 2 + u2;
        const unsigned short* g = Bpk + ((size_t)(nt * 13 + kt + 1) * 64 + lane) * 8;
        __builtin_amdgcn_global_load_lds(
            (const __attribute__((address_space(1))) void*)g,
            (__attribute__((address_space(3))) void*)&Blds[(kt + 1) % 3][nt * 1024], 16, 0, 0);
      }
      asm volatile("s_waitcnt vmcnt(2)" ::: "memory");
    } else {
      asm volatile("s_waitcnt vmcnt(0)" ::: "memory");
    }
    __builtin_amdgcn_s_barrier();
    // ---- MFMA: 8 N-tiles x 2 M-tiles ----
    const char* bb = Blds[kt % 3];
#pragma unroll
    for (int nt = 0; nt < 8; ++nt) {
      short8 bf = *(const short8*)(bb + nt * 1024 + lane * 16);
      acc[0][nt] = __builtin_amdgcn_mfma_f32_16x16x32_bf16(a0, bf, acc[0][nt], 0, 0, 0);
      acc[1][nt] = __builtin_amdgcn_mfma_f32_16x16x32_bf16(a1, bf, acc[1][nt], 0, 0, 0);
    }
  }

  // ---- epilogue: LayerNorm over 128 cols (16 lanes x 8 nt) + store ----
  float gg[8], bb8[8];
#pragma unroll
  for (int nt = 0; nt < 8; ++nt) {
    gg[nt] = gamma[nt * 16 + r];
    bb8[nt] = beta[nt * 16 + r];
  }
#pragma unroll
  for (int t = 0; t < 2; ++t) {
#pragma unroll
    for (int reg = 0; reg < 4; ++reg) {
      float s = 0.f, ss = 0.f;
#pragma unroll
      for (int nt = 0; nt < 8; ++nt) {
        float v = acc[t][nt][reg];
        s += v; ss += v * v;
      }
#pragma unroll
      for (int m = 1; m <= 8; m <<= 1) {
        s += __shfl_xor(s, m, 64);
        ss += __shfl_xor(ss, m, 64);
      }
      float mu = s * (1.0f / 128.0f);
      float var = ss * (1.0f / 128.0f) - mu * mu;
      float rstd = rsqrtf(var + 1e-5f);
      long grow = E0 + wv * 32 + t * 16 + q * 4 + reg;
      float* op = out + grow * 128 + r;
#pragma unroll
      for (int nt = 0; nt < 8; ++nt)
        op[nt * 16] = (acc[t][nt][reg] - mu) * rstd * gg[nt] + bb8[nt];
    }
  }
}

extern "C" void kernel_launch(void* const* d_in, const int* in_sizes, int n_in,
                              void* d_out, int out_size, void* d_ws, size_t ws_size,
                              hipStream_t stream) {
  const float* x = (const float*)d_in[0];
  const float* mask = (const float*)d_in[1];
  const int* ridx = (const int*)d_in[2];
  const int* chains = (const int*)d_in[3];
  const float* w_pos = (const float*)d_in[4];
  const float* b_pos = (const float*)d_in[5];
  const float* w_edge = (const float*)d_in[6];
  const float* gamma = (const float*)d_in[7];
  const float* beta = (const float*)d_in[8];
  float* out = (float*)d_out;

  const size_t n_rows = (size_t)BATCH * NRES;   // 8192
  const size_t n_edges = n_rows * TOPK;         // 393216
  float* atoms = (float*)d_ws;                                        // 8192*16 f
  int* nidx = (int*)((char*)d_ws + 4 * n_rows * 16);                  // n_edges i
  float* dnb = (float*)((char*)d_ws + 4 * (n_rows * 16 + n_edges));   // n_edges f
  unsigned short* Bpk =
      (unsigned short*)((char*)d_ws + 4 * (n_rows * 16 + 2 * n_edges));  // 53248 bf16
  float* idx_out = out + n_edges * EDGEF;

  atoms_kernel<<<(int)((n_rows + 255) / 256), 256, 0, stream>>>(x, atoms);
  prepack_kernel<<<26, 256, 0, stream>>>(w_edge, Bpk);
  topk_kernel<<<(int)(n_rows / 4), 256, 0, stream>>>(atoms, mask, nidx, dnb, idx_out);
  edge_mfma_kernel<<<(int)(n_edges / 128), 256, 0, stream>>>(
      atoms, nidx, dnb, ridx, chains, w_pos, b_pos, Bpk, gamma, beta, out);
}